// Round 2
// baseline (138.326 us; speedup 1.0000x reference)
//
#include <hip/hip_runtime.h>
#include <math.h>

#define NG 2048
#define IMG_W 128
#define IMG_H 128
#define NPIX (IMG_W * IMG_H)
#define NSEG 8
#define SEG_SIZE (NG / NSEG) // 256

// 48-byte gaussian record = 3 x float4 for ds_read_b128 staging
struct __align__(16) GS {
    float u, v, ca, cb;     // center, conic a, conic b
    float cc, alpha, cr, cg; // conic c, opacity (0 if invalid), color r,g
    float cbl, z, pad1, pad2;
};

// ---------------------------------------------------------------------------
// Kernel AB: preprocess all gaussians + bitonic argsort by z + gather sorted
// Single block of 1024 threads.
// ---------------------------------------------------------------------------
__global__ __launch_bounds__(1024) void prep_sort_kernel(
    const float* __restrict__ mean, const float* __restrict__ qvec,
    const float* __restrict__ svec_raw, const float* __restrict__ color_raw,
    const float* __restrict__ alpha_raw, const float* __restrict__ viewmat,
    const float* __restrict__ intrins, GS* __restrict__ graw,
    GS* __restrict__ gsorted)
{
    __shared__ float skey[NG];
    __shared__ int   sval[NG];
    const int tid = threadIdx.x;

    const float fx = intrins[0], fy = intrins[1], cx = intrins[2], cy = intrins[3];
    const float R00 = viewmat[0], R01 = viewmat[1], R02 = viewmat[2],  t0 = viewmat[3];
    const float R10 = viewmat[4], R11 = viewmat[5], R12 = viewmat[6],  t1 = viewmat[7];
    const float R20 = viewmat[8], R21 = viewmat[9], R22 = viewmat[10], t2 = viewmat[11];

    for (int g = tid; g < NG; g += 1024) {
        float mx = mean[g * 3 + 0], my = mean[g * 3 + 1], mz = mean[g * 3 + 2];
        float x = R00 * mx + R01 * my + R02 * mz + t0;
        float y = R10 * mx + R11 * my + R12 * mz + t1;
        float z = R20 * mx + R21 * my + R22 * mz + t2;
        float zc = fmaxf(z, 0.001f);

        float qw = qvec[g * 4 + 0], qx = qvec[g * 4 + 1];
        float qy = qvec[g * 4 + 2], qz = qvec[g * 4 + 3];
        float qn = rsqrtf(qw * qw + qx * qx + qy * qy + qz * qz);
        qw *= qn; qx *= qn; qy *= qn; qz *= qn;
        float Rq00 = 1.f - 2.f * (qy * qy + qz * qz), Rq01 = 2.f * (qx * qy - qw * qz), Rq02 = 2.f * (qx * qz + qw * qy);
        float Rq10 = 2.f * (qx * qy + qw * qz), Rq11 = 1.f - 2.f * (qx * qx + qz * qz), Rq12 = 2.f * (qy * qz - qw * qx);
        float Rq20 = 2.f * (qx * qz - qw * qy), Rq21 = 2.f * (qy * qz + qw * qx), Rq22 = 1.f - 2.f * (qx * qx + qy * qy);

        float s0 = expf(svec_raw[g * 3 + 0]);
        float s1 = expf(svec_raw[g * 3 + 1]);
        float s2 = expf(svec_raw[g * 3 + 2]);
        // M = Rq * diag(s)
        float M00 = Rq00 * s0, M01 = Rq01 * s1, M02 = Rq02 * s2;
        float M10 = Rq10 * s0, M11 = Rq11 * s1, M12 = Rq12 * s2;
        float M20 = Rq20 * s0, M21 = Rq21 * s1, M22 = Rq22 * s2;

        float iz = 1.0f / zc;
        float J00 = fx * iz, J02 = -fx * x * iz * iz;
        float J11 = fy * iz, J12 = -fy * y * iz * iz;
        // T2 = J @ Rw (2x3); J row0 = [J00, 0, J02], row1 = [0, J11, J12]
        float T00 = J00 * R00 + J02 * R20;
        float T01 = J00 * R01 + J02 * R21;
        float T02 = J00 * R02 + J02 * R22;
        float T10 = J11 * R10 + J12 * R20;
        float T11 = J11 * R11 + J12 * R21;
        float T12 = J11 * R12 + J12 * R22;
        // TM = T2 @ M (2x3)
        float TM00 = T00 * M00 + T01 * M10 + T02 * M20;
        float TM01 = T00 * M01 + T01 * M11 + T02 * M21;
        float TM02 = T00 * M02 + T01 * M12 + T02 * M22;
        float TM10 = T10 * M00 + T11 * M10 + T12 * M20;
        float TM11 = T10 * M01 + T11 * M11 + T12 * M21;
        float TM12 = T10 * M02 + T11 * M12 + T12 * M22;
        // cov2d = TM @ TM^T + 0.3 I
        float a = TM00 * TM00 + TM01 * TM01 + TM02 * TM02 + 0.3f;
        float b = TM00 * TM10 + TM01 * TM11 + TM02 * TM12;
        float c = TM10 * TM10 + TM11 * TM11 + TM12 * TM12 + 0.3f;
        float det = a * c - b * b;
        float det_safe = fmaxf(det, 1e-8f);
        float inv_det = 1.0f / det_safe;
        bool valid = (z > 0.2f) && (det > 0.0f);
        float alpha = 1.0f / (1.0f + expf(-alpha_raw[g]));

        GS gs;
        gs.u = fx * x * iz + cx;
        gs.v = fy * y * iz + cy;
        gs.ca = c * inv_det;
        gs.cb = -b * inv_det;
        gs.cc = a * inv_det;
        gs.alpha = valid ? alpha : 0.0f;
        gs.cr  = 1.0f / (1.0f + expf(-color_raw[g * 3 + 0]));
        gs.cg  = 1.0f / (1.0f + expf(-color_raw[g * 3 + 1]));
        gs.cbl = 1.0f / (1.0f + expf(-color_raw[g * 3 + 2]));
        gs.z = z; gs.pad1 = 0.0f; gs.pad2 = 0.0f;
        graw[g] = gs;
        skey[g] = z;
        sval[g] = g;
    }
    __syncthreads();

    // Bitonic sort ascending on (skey, sval). Pairs within a pass are
    // disjoint, so no sync needed inside the i-loop, only between passes.
    for (int k = 2; k <= NG; k <<= 1) {
        for (int j = k >> 1; j > 0; j >>= 1) {
            for (int i = tid; i < NG; i += 1024) {
                int ixj = i ^ j;
                if (ixj > i) {
                    bool up = ((i & k) == 0);
                    float ki = skey[i], kj = skey[ixj];
                    if ((ki > kj) == up) {
                        skey[i] = kj; skey[ixj] = ki;
                        int tv = sval[i]; sval[i] = sval[ixj]; sval[ixj] = tv;
                    }
                }
            }
            __syncthreads();
        }
    }

    for (int i = tid; i < NG; i += 1024) {
        gsorted[i] = graw[sval[i]];
    }
}

// ---------------------------------------------------------------------------
// Kernel C: per-(pixel-tile, segment) partial compositing.
// grid (16,16,NSEG), block 64 = 8x8 pixel tile. Gaussians staged in LDS;
// all lanes read the same record -> broadcast, conflict-free.
// ---------------------------------------------------------------------------
__global__ __launch_bounds__(64) void composite_partial_kernel(
    const GS* __restrict__ gsorted, float4* __restrict__ partial)
{
    __shared__ float4 sg[SEG_SIZE * 3]; // 12 KiB
    const int tx = threadIdx.x & 7, ty = threadIdx.x >> 3;
    const int px = blockIdx.x * 8 + tx;
    const int py = blockIdx.y * 8 + ty;
    const int seg = blockIdx.z;

    const float4* gsrc = (const float4*)(gsorted + seg * SEG_SIZE);
    for (int i = threadIdx.x; i < SEG_SIZE * 3; i += 64)
        sg[i] = gsrc[i];
    __syncthreads();

    const float fpx = px + 0.5f, fpy = py + 0.5f;
    float T = 1.0f, Cr = 0.0f, Cg = 0.0f, Cb = 0.0f;
    for (int n = 0; n < SEG_SIZE; ++n) {
        float4 f0 = sg[n * 3 + 0];
        float4 f1 = sg[n * 3 + 1];
        float4 f2 = sg[n * 3 + 2];
        float dx = fpx - f0.x;
        float dy = fpy - f0.y;
        float power = -0.5f * (f0.z * dx * dx + f1.x * dy * dy) - f0.w * dx * dy;
        float g = __expf(fminf(power, 0.0f));
        float a = fminf(0.99f, f1.y * g);
        float w = a * T;
        Cr += w * f1.z;
        Cg += w * f1.w;
        Cb += w * f2.x;
        T *= (1.0f - a);
    }
    int pix = py * IMG_W + px;
    partial[seg * NPIX + pix] = make_float4(Cr, Cg, Cb, T);
}

// ---------------------------------------------------------------------------
// Kernel D: in-order combine of the NSEG partials + background.
// ---------------------------------------------------------------------------
__global__ __launch_bounds__(256) void combine_kernel(
    const float4* __restrict__ partial, const float* __restrict__ bg,
    float* __restrict__ out)
{
    int pix = blockIdx.x * blockDim.x + threadIdx.x;
    if (pix >= NPIX) return;
    float T = 1.0f, Cr = 0.0f, Cg = 0.0f, Cb = 0.0f;
    for (int s = 0; s < NSEG; ++s) {
        float4 p = partial[s * NPIX + pix];
        Cr += T * p.x;
        Cg += T * p.y;
        Cb += T * p.z;
        T *= p.w;
    }
    out[pix * 3 + 0] = Cr + T * bg[0];
    out[pix * 3 + 1] = Cg + T * bg[1];
    out[pix * 3 + 2] = Cb + T * bg[2];
}

extern "C" void kernel_launch(void* const* d_in, const int* in_sizes, int n_in,
                              void* d_out, int out_size, void* d_ws, size_t ws_size,
                              hipStream_t stream)
{
    const float* mean      = (const float*)d_in[0];
    const float* qvec      = (const float*)d_in[1];
    const float* svec_raw  = (const float*)d_in[2];
    const float* color_raw = (const float*)d_in[3];
    const float* alpha_raw = (const float*)d_in[4];
    const float* bg        = (const float*)d_in[5];
    const float* viewmat   = (const float*)d_in[6];
    const float* intrins   = (const float*)d_in[7];

    char* ws = (char*)d_ws;
    GS* graw      = (GS*)ws;                                 // 98304 B
    GS* gsorted   = (GS*)(ws + NG * sizeof(GS));             // 98304 B
    float4* partial = (float4*)(ws + 2 * NG * sizeof(GS));   // NSEG*NPIX*16 = 2 MiB

    hipLaunchKernelGGL(prep_sort_kernel, dim3(1), dim3(1024), 0, stream,
                       mean, qvec, svec_raw, color_raw, alpha_raw, viewmat,
                       intrins, graw, gsorted);
    hipLaunchKernelGGL(composite_partial_kernel, dim3(16, 16, NSEG), dim3(64),
                       0, stream, gsorted, partial);
    hipLaunchKernelGGL(combine_kernel, dim3((NPIX + 255) / 256), dim3(256),
                       0, stream, partial, bg, (float*)d_out);
}

// Round 3
// 97.461 us; speedup vs baseline: 1.4193x; 1.4193x over previous
//
#include <hip/hip_runtime.h>
#include <hip/hip_fp16.h>
#include <math.h>

#define NG 2048
#define IMG_W 128
#define IMG_H 128
#define NPIX (IMG_W * IMG_H)
#define L2E 1.4426950408889634f

// 32-byte packed gaussian record = 2 x float4 for ds_read_b128 staging.
// A = -0.5*log2e*conic_a, B = -log2e*conic_b, C = -0.5*log2e*conic_c
// so power_log2 = A*dx^2 + B*dx*dy + C*dy^2 and g = exp2(min(power_log2,0)).
// Colors packed as f16 (abs err <= 5e-4, threshold is 1.9e-2).
struct __align__(16) PG {
    float u, v, A, B;
    float C, alpha;
    unsigned int rg;   // half2 (cr, cg)
    unsigned int bl;   // half cb in low 16 bits
};

// ---------------------------------------------------------------------------
// Kernel 1: per-gaussian preprocessing. 8 blocks x 256 threads.
// ---------------------------------------------------------------------------
__global__ __launch_bounds__(256) void prep_kernel(
    const float* __restrict__ mean, const float* __restrict__ qvec,
    const float* __restrict__ svec_raw, const float* __restrict__ color_raw,
    const float* __restrict__ alpha_raw, const float* __restrict__ viewmat,
    const float* __restrict__ intrins, PG* __restrict__ graw,
    float* __restrict__ zbuf)
{
    const int g = blockIdx.x * 256 + threadIdx.x;
    if (g >= NG) return;

    const float fx = intrins[0], fy = intrins[1], cx = intrins[2], cy = intrins[3];
    const float R00 = viewmat[0], R01 = viewmat[1], R02 = viewmat[2],  t0 = viewmat[3];
    const float R10 = viewmat[4], R11 = viewmat[5], R12 = viewmat[6],  t1 = viewmat[7];
    const float R20 = viewmat[8], R21 = viewmat[9], R22 = viewmat[10], t2 = viewmat[11];

    float mx = mean[g * 3 + 0], my = mean[g * 3 + 1], mz = mean[g * 3 + 2];
    float x = R00 * mx + R01 * my + R02 * mz + t0;
    float y = R10 * mx + R11 * my + R12 * mz + t1;
    float z = R20 * mx + R21 * my + R22 * mz + t2;
    float zc = fmaxf(z, 0.001f);

    float qw = qvec[g * 4 + 0], qx = qvec[g * 4 + 1];
    float qy = qvec[g * 4 + 2], qz = qvec[g * 4 + 3];
    float qn = rsqrtf(qw * qw + qx * qx + qy * qy + qz * qz);
    qw *= qn; qx *= qn; qy *= qn; qz *= qn;
    float Rq00 = 1.f - 2.f * (qy * qy + qz * qz), Rq01 = 2.f * (qx * qy - qw * qz), Rq02 = 2.f * (qx * qz + qw * qy);
    float Rq10 = 2.f * (qx * qy + qw * qz), Rq11 = 1.f - 2.f * (qx * qx + qz * qz), Rq12 = 2.f * (qy * qz - qw * qx);
    float Rq20 = 2.f * (qx * qz - qw * qy), Rq21 = 2.f * (qy * qz + qw * qx), Rq22 = 1.f - 2.f * (qx * qx + qy * qy);

    float s0 = expf(svec_raw[g * 3 + 0]);
    float s1 = expf(svec_raw[g * 3 + 1]);
    float s2 = expf(svec_raw[g * 3 + 2]);
    float M00 = Rq00 * s0, M01 = Rq01 * s1, M02 = Rq02 * s2;
    float M10 = Rq10 * s0, M11 = Rq11 * s1, M12 = Rq12 * s2;
    float M20 = Rq20 * s0, M21 = Rq21 * s1, M22 = Rq22 * s2;

    float iz = 1.0f / zc;
    float J00 = fx * iz, J02 = -fx * x * iz * iz;
    float J11 = fy * iz, J12 = -fy * y * iz * iz;
    float T00 = J00 * R00 + J02 * R20;
    float T01 = J00 * R01 + J02 * R21;
    float T02 = J00 * R02 + J02 * R22;
    float T10 = J11 * R10 + J12 * R20;
    float T11 = J11 * R11 + J12 * R21;
    float T12 = J11 * R12 + J12 * R22;
    float TM00 = T00 * M00 + T01 * M10 + T02 * M20;
    float TM01 = T00 * M01 + T01 * M11 + T02 * M21;
    float TM02 = T00 * M02 + T01 * M12 + T02 * M22;
    float TM10 = T10 * M00 + T11 * M10 + T12 * M20;
    float TM11 = T10 * M01 + T11 * M11 + T12 * M21;
    float TM12 = T10 * M02 + T11 * M12 + T12 * M22;
    float a = TM00 * TM00 + TM01 * TM01 + TM02 * TM02 + 0.3f;
    float b = TM00 * TM10 + TM01 * TM11 + TM02 * TM12;
    float c = TM10 * TM10 + TM11 * TM11 + TM12 * TM12 + 0.3f;
    float det = a * c - b * b;
    float det_safe = fmaxf(det, 1e-8f);
    float inv_det = 1.0f / det_safe;
    bool valid = (z > 0.2f) && (det > 0.0f);
    float alpha = 1.0f / (1.0f + expf(-alpha_raw[g]));

    float conic_a = c * inv_det;
    float conic_b = -b * inv_det;
    float conic_c = a * inv_det;

    PG pg;
    pg.u = fx * x * iz + cx;
    pg.v = fy * y * iz + cy;
    pg.A = -0.5f * L2E * conic_a;
    pg.B = -L2E * conic_b;
    pg.C = -0.5f * L2E * conic_c;
    pg.alpha = valid ? alpha : 0.0f;
    float cr  = 1.0f / (1.0f + expf(-color_raw[g * 3 + 0]));
    float cg  = 1.0f / (1.0f + expf(-color_raw[g * 3 + 1]));
    float cbl = 1.0f / (1.0f + expf(-color_raw[g * 3 + 2]));
    __half2 hrg = __floats2half2_rn(cr, cg);
    pg.rg = *reinterpret_cast<unsigned int*>(&hrg);
    __half hb = __float2half_rn(cbl);
    pg.bl = (unsigned int)(*reinterpret_cast<unsigned short*>(&hb));
    graw[g] = pg;
    zbuf[g] = z;
}

// ---------------------------------------------------------------------------
// Kernel 2: rank-count argsort + scatter. One wave per gaussian.
// rank[g] = #{h : z[h] < z[g] or (z[h]==z[g] and h<g)} -> stable permutation.
// 512 blocks x 256 threads = 2048 waves.
// ---------------------------------------------------------------------------
__global__ __launch_bounds__(256) void rank_scatter_kernel(
    const float* __restrict__ zbuf, const PG* __restrict__ graw,
    PG* __restrict__ gsorted)
{
    const int wave = (blockIdx.x * 256 + threadIdx.x) >> 6; // == gaussian id
    const int lane = threadIdx.x & 63;
    const int g = wave;
    const float zg = zbuf[g];
    int cnt = 0;
#pragma unroll
    for (int k = 0; k < NG / 64; ++k) {
        int h = k * 64 + lane;
        float zh = zbuf[h];
        bool lt = (zh < zg) || ((zh == zg) && (h < g));
        cnt += lt ? 1 : 0;
    }
#pragma unroll
    for (int off = 32; off >= 1; off >>= 1)
        cnt += __shfl_down(cnt, off);
    int rank = __shfl(cnt, 0);
    if (lane < 2) {
        ((float4*)(gsorted + rank))[lane] = ((const float4*)(graw + g))[lane];
    }
}

// ---------------------------------------------------------------------------
// Kernel 3: segmented compositing. Block = 64 threads = 16x16 pixel tile,
// 4 pixels/thread sharing a column (dx, dx^2, A*dx^2, B*dx shared).
// grid (8, 8, NSEG). Gaussians staged in LDS, broadcast reads.
// ---------------------------------------------------------------------------
template <int NSEG>
__global__ __launch_bounds__(64) void composite_kernel(
    const PG* __restrict__ gsorted, float4* __restrict__ partial)
{
    constexpr int SEG = NG / NSEG;
    __shared__ float4 sg[SEG * 2];
    const int t = threadIdx.x;
    const int seg = blockIdx.z;
    const int col = blockIdx.x * 16 + (t & 15);
    const int row0 = blockIdx.y * 16 + (t >> 4) * 4;

    const float4* src = (const float4*)(gsorted + seg * SEG);
#pragma unroll
    for (int i = t; i < SEG * 2; i += 64) sg[i] = src[i];
    __syncthreads();

    const float fpx = col + 0.5f;
    const float fpy0 = row0 + 0.5f;
    float T0 = 1.f, T1 = 1.f, T2 = 1.f, T3 = 1.f;
    float Cr0 = 0.f, Cg0 = 0.f, Cb0 = 0.f;
    float Cr1 = 0.f, Cg1 = 0.f, Cb1 = 0.f;
    float Cr2 = 0.f, Cg2 = 0.f, Cb2 = 0.f;
    float Cr3 = 0.f, Cg3 = 0.f, Cb3 = 0.f;

#pragma unroll 4
    for (int n = 0; n < SEG; ++n) {
        float4 f0 = sg[2 * n + 0];
        float4 f1 = sg[2 * n + 1];
        float dx = fpx - f0.x;
        float dx2 = dx * dx;
        float adx2 = f0.z * dx2;
        float bdx = f0.w * dx;
        float alpha = f1.y;
        union { float f; __half2 h; } urg; urg.f = f1.z;
        union { float f; __half2 h; } ubl; ubl.f = f1.w;
        float cr = __half2float(__low2half(urg.h));
        float cg = __half2float(__high2half(urg.h));
        float cb = __half2float(__low2half(ubl.h));

        float dy, p, gv, a, w;

        dy = fpy0 - f0.y;
        p = fminf(fmaf(dy, fmaf(f1.x, dy, bdx), adx2), 0.f);
        gv = exp2f(p);
        a = fminf(0.99f, alpha * gv);
        w = a * T0;
        Cr0 = fmaf(w, cr, Cr0); Cg0 = fmaf(w, cg, Cg0); Cb0 = fmaf(w, cb, Cb0);
        T0 = fmaf(-a, T0, T0);

        dy = (fpy0 + 1.f) - f0.y;
        p = fminf(fmaf(dy, fmaf(f1.x, dy, bdx), adx2), 0.f);
        gv = exp2f(p);
        a = fminf(0.99f, alpha * gv);
        w = a * T1;
        Cr1 = fmaf(w, cr, Cr1); Cg1 = fmaf(w, cg, Cg1); Cb1 = fmaf(w, cb, Cb1);
        T1 = fmaf(-a, T1, T1);

        dy = (fpy0 + 2.f) - f0.y;
        p = fminf(fmaf(dy, fmaf(f1.x, dy, bdx), adx2), 0.f);
        gv = exp2f(p);
        a = fminf(0.99f, alpha * gv);
        w = a * T2;
        Cr2 = fmaf(w, cr, Cr2); Cg2 = fmaf(w, cg, Cg2); Cb2 = fmaf(w, cb, Cb2);
        T2 = fmaf(-a, T2, T2);

        dy = (fpy0 + 3.f) - f0.y;
        p = fminf(fmaf(dy, fmaf(f1.x, dy, bdx), adx2), 0.f);
        gv = exp2f(p);
        a = fminf(0.99f, alpha * gv);
        w = a * T3;
        Cr3 = fmaf(w, cr, Cr3); Cg3 = fmaf(w, cg, Cg3); Cb3 = fmaf(w, cb, Cb3);
        T3 = fmaf(-a, T3, T3);
    }

    float4* dst = partial + (size_t)seg * NPIX + row0 * IMG_W + col;
    dst[0 * IMG_W] = make_float4(Cr0, Cg0, Cb0, T0);
    dst[1 * IMG_W] = make_float4(Cr1, Cg1, Cb1, T1);
    dst[2 * IMG_W] = make_float4(Cr2, Cg2, Cb2, T2);
    dst[3 * IMG_W] = make_float4(Cr3, Cg3, Cb3, T3);
}

// ---------------------------------------------------------------------------
// Kernel 4: in-order combine of NSEG partials + background. 256 blocks x 64.
// ---------------------------------------------------------------------------
template <int NSEG>
__global__ __launch_bounds__(64) void combine_kernel(
    const float4* __restrict__ partial, const float* __restrict__ bg,
    float* __restrict__ out)
{
    int pix = blockIdx.x * 64 + threadIdx.x;
    float T = 1.0f, Cr = 0.0f, Cg = 0.0f, Cb = 0.0f;
#pragma unroll
    for (int s = 0; s < NSEG; ++s) {
        float4 p = partial[s * NPIX + pix];
        Cr = fmaf(T, p.x, Cr);
        Cg = fmaf(T, p.y, Cg);
        Cb = fmaf(T, p.z, Cb);
        T *= p.w;
    }
    out[pix * 3 + 0] = Cr + T * bg[0];
    out[pix * 3 + 1] = Cg + T * bg[1];
    out[pix * 3 + 2] = Cb + T * bg[2];
}

template <int NSEG>
static void launch_pipeline(const float* mean, const float* qvec,
                            const float* svec_raw, const float* color_raw,
                            const float* alpha_raw, const float* bg,
                            const float* viewmat, const float* intrins,
                            float* out, char* ws, hipStream_t stream)
{
    PG* graw      = (PG*)ws;                          // 64 KiB
    float* zbuf   = (float*)(ws + NG * sizeof(PG));   // 8 KiB
    PG* gsorted   = (PG*)(ws + NG * sizeof(PG) + NG * sizeof(float));
    float4* partial = (float4*)(ws + 2 * NG * sizeof(PG) + NG * sizeof(float));

    hipLaunchKernelGGL(prep_kernel, dim3(NG / 256), dim3(256), 0, stream,
                       mean, qvec, svec_raw, color_raw, alpha_raw, viewmat,
                       intrins, graw, zbuf);
    hipLaunchKernelGGL(rank_scatter_kernel, dim3(NG * 64 / 256), dim3(256),
                       0, stream, zbuf, graw, gsorted);
    hipLaunchKernelGGL((composite_kernel<NSEG>), dim3(8, 8, NSEG), dim3(64),
                       0, stream, gsorted, partial);
    hipLaunchKernelGGL((combine_kernel<NSEG>), dim3(NPIX / 64), dim3(64),
                       0, stream, partial, bg, out);
}

extern "C" void kernel_launch(void* const* d_in, const int* in_sizes, int n_in,
                              void* d_out, int out_size, void* d_ws, size_t ws_size,
                              hipStream_t stream)
{
    const float* mean      = (const float*)d_in[0];
    const float* qvec      = (const float*)d_in[1];
    const float* svec_raw  = (const float*)d_in[2];
    const float* color_raw = (const float*)d_in[3];
    const float* alpha_raw = (const float*)d_in[4];
    const float* bg        = (const float*)d_in[5];
    const float* viewmat   = (const float*)d_in[6];
    const float* intrins   = (const float*)d_in[7];
    char* ws = (char*)d_ws;
    float* out = (float*)d_out;

    const size_t fixed = 2 * NG * sizeof(PG) + NG * sizeof(float);
    if (ws_size >= fixed + (size_t)32 * NPIX * sizeof(float4)) {
        launch_pipeline<32>(mean, qvec, svec_raw, color_raw, alpha_raw, bg,
                            viewmat, intrins, out, ws, stream);
    } else if (ws_size >= fixed + (size_t)16 * NPIX * sizeof(float4)) {
        launch_pipeline<16>(mean, qvec, svec_raw, color_raw, alpha_raw, bg,
                            viewmat, intrins, out, ws, stream);
    } else {
        launch_pipeline<8>(mean, qvec, svec_raw, color_raw, alpha_raw, bg,
                           viewmat, intrins, out, ws, stream);
    }
}

// Round 4
// 81.933 us; speedup vs baseline: 1.6883x; 1.1895x over previous
//
#include <hip/hip_runtime.h>
#include <hip/hip_fp16.h>
#include <math.h>

#define NG 2048
#define IMG_W 128
#define IMG_H 128
#define NPIX (IMG_W * IMG_H)
#define L2E 1.4426950408889634f

// 32-byte packed gaussian record = 2 x float4 for ds_read_b128 staging.
// A = -0.5*log2e*conic_a, B = -log2e*conic_b, C = -0.5*log2e*conic_c
// so power_log2 = A*dx^2 + B*dx*dy + C*dy^2 and g = exp2(min(power_log2,0)).
// f0 = (u, v, A, B); f1 = (C, alpha_f32, (cr,cg) half2, (cb, r2) half2)
// r2 = cull radius^2: skip gaussian for a tile if min dist^2 > r2
// (power_log2 <= -0.5*L2E*lam_min*d^2; THR=24 -> r2 = 2*24/(L2E*lam_min)).
struct __align__(16) PG {
    float u, v, A, B;
    float C, alpha;
    unsigned int rg;    // half2 (cr, cg)
    unsigned int b_r2;  // half2 (cb, r2)
};

// ---------------------------------------------------------------------------
// Kernel 1: per-gaussian preprocessing. 8 blocks x 256 threads.
// ---------------------------------------------------------------------------
__global__ __launch_bounds__(256) void prep_kernel(
    const float* __restrict__ mean, const float* __restrict__ qvec,
    const float* __restrict__ svec_raw, const float* __restrict__ color_raw,
    const float* __restrict__ alpha_raw, const float* __restrict__ viewmat,
    const float* __restrict__ intrins, PG* __restrict__ graw,
    float* __restrict__ zbuf)
{
    const int g = blockIdx.x * 256 + threadIdx.x;
    if (g >= NG) return;

    const float fx = intrins[0], fy = intrins[1], cx = intrins[2], cy = intrins[3];
    const float R00 = viewmat[0], R01 = viewmat[1], R02 = viewmat[2],  t0 = viewmat[3];
    const float R10 = viewmat[4], R11 = viewmat[5], R12 = viewmat[6],  t1 = viewmat[7];
    const float R20 = viewmat[8], R21 = viewmat[9], R22 = viewmat[10], t2 = viewmat[11];

    float mx = mean[g * 3 + 0], my = mean[g * 3 + 1], mz = mean[g * 3 + 2];
    float x = R00 * mx + R01 * my + R02 * mz + t0;
    float y = R10 * mx + R11 * my + R12 * mz + t1;
    float z = R20 * mx + R21 * my + R22 * mz + t2;
    float zc = fmaxf(z, 0.001f);

    float qw = qvec[g * 4 + 0], qx = qvec[g * 4 + 1];
    float qy = qvec[g * 4 + 2], qz = qvec[g * 4 + 3];
    float qn = rsqrtf(qw * qw + qx * qx + qy * qy + qz * qz);
    qw *= qn; qx *= qn; qy *= qn; qz *= qn;
    float Rq00 = 1.f - 2.f * (qy * qy + qz * qz), Rq01 = 2.f * (qx * qy - qw * qz), Rq02 = 2.f * (qx * qz + qw * qy);
    float Rq10 = 2.f * (qx * qy + qw * qz), Rq11 = 1.f - 2.f * (qx * qx + qz * qz), Rq12 = 2.f * (qy * qz - qw * qx);
    float Rq20 = 2.f * (qx * qz - qw * qy), Rq21 = 2.f * (qy * qz + qw * qx), Rq22 = 1.f - 2.f * (qx * qx + qy * qy);

    float s0 = expf(svec_raw[g * 3 + 0]);
    float s1 = expf(svec_raw[g * 3 + 1]);
    float s2 = expf(svec_raw[g * 3 + 2]);
    float M00 = Rq00 * s0, M01 = Rq01 * s1, M02 = Rq02 * s2;
    float M10 = Rq10 * s0, M11 = Rq11 * s1, M12 = Rq12 * s2;
    float M20 = Rq20 * s0, M21 = Rq21 * s1, M22 = Rq22 * s2;

    float iz = 1.0f / zc;
    float J00 = fx * iz, J02 = -fx * x * iz * iz;
    float J11 = fy * iz, J12 = -fy * y * iz * iz;
    float T00 = J00 * R00 + J02 * R20;
    float T01 = J00 * R01 + J02 * R21;
    float T02 = J00 * R02 + J02 * R22;
    float T10 = J11 * R10 + J12 * R20;
    float T11 = J11 * R11 + J12 * R21;
    float T12 = J11 * R12 + J12 * R22;
    float TM00 = T00 * M00 + T01 * M10 + T02 * M20;
    float TM01 = T00 * M01 + T01 * M11 + T02 * M21;
    float TM02 = T00 * M02 + T01 * M12 + T02 * M22;
    float TM10 = T10 * M00 + T11 * M10 + T12 * M20;
    float TM11 = T10 * M01 + T11 * M11 + T12 * M21;
    float TM12 = T10 * M02 + T11 * M12 + T12 * M22;
    float a = TM00 * TM00 + TM01 * TM01 + TM02 * TM02 + 0.3f;
    float b = TM00 * TM10 + TM01 * TM11 + TM02 * TM12;
    float c = TM10 * TM10 + TM11 * TM11 + TM12 * TM12 + 0.3f;
    float det = a * c - b * b;
    float det_safe = fmaxf(det, 1e-8f);
    float inv_det = 1.0f / det_safe;
    bool valid = (z > 0.2f) && (det > 0.0f);
    float alpha = 1.0f / (1.0f + expf(-alpha_raw[g]));

    float conic_a = c * inv_det;
    float conic_b = -b * inv_det;
    float conic_c = a * inv_det;

    // cull radius^2 from conic lambda_min (THR = 24 log2-units; slack 1.05x)
    float half_tr = 0.5f * (conic_a + conic_c);
    float half_df = 0.5f * (conic_a - conic_c);
    float lam_min = half_tr - sqrtf(half_df * half_df + conic_b * conic_b);
    float r2 = (lam_min > 1e-20f) ? (1.05f * 2.0f * 24.0f / (L2E * lam_min)) : 3.0e38f;
    if (!valid) r2 = -1.0f; // skip always

    PG pg;
    pg.u = fx * x * iz + cx;
    pg.v = fy * y * iz + cy;
    pg.A = -0.5f * L2E * conic_a;
    pg.B = -L2E * conic_b;
    pg.C = -0.5f * L2E * conic_c;
    pg.alpha = alpha;
    float cr  = 1.0f / (1.0f + expf(-color_raw[g * 3 + 0]));
    float cg  = 1.0f / (1.0f + expf(-color_raw[g * 3 + 1]));
    float cbl = 1.0f / (1.0f + expf(-color_raw[g * 3 + 2]));
    __half2 hrg = __floats2half2_rn(cr, cg);
    pg.rg = *reinterpret_cast<unsigned int*>(&hrg);
    // (cb, r2) as half2; r2 > 65504 rounds to +inf -> always-keep (correctly
    // conservative); r2 = -1 -> always-skip (invalid gaussian).
    __half2 hbr = __halves2half2(__float2half_rn(cbl), __float2half_rn(r2));
    pg.b_r2 = *reinterpret_cast<unsigned int*>(&hbr);
    graw[g] = pg;
    zbuf[g] = z;
}

// ---------------------------------------------------------------------------
// Kernel 2: rank-count argsort + scatter. One wave per gaussian, float4 keys.
// rank[g] = #{h : z[h] < z[g] or (z[h]==z[g] and h<g)} -> stable permutation.
// ---------------------------------------------------------------------------
__global__ __launch_bounds__(256) void rank_scatter_kernel(
    const float* __restrict__ zbuf, const PG* __restrict__ graw,
    PG* __restrict__ gsorted)
{
    const int g = (blockIdx.x * 256 + threadIdx.x) >> 6; // gaussian id
    const int lane = threadIdx.x & 63;
    const float zg = zbuf[g];
    const float4* z4 = (const float4*)zbuf;
    int cnt = 0;
#pragma unroll
    for (int k = 0; k < NG / 256; ++k) {
        int idx = k * 64 + lane;
        float4 zz = z4[idx];
        int h = idx * 4;
        cnt += ((zz.x < zg) || ((zz.x == zg) && (h + 0 < g))) ? 1 : 0;
        cnt += ((zz.y < zg) || ((zz.y == zg) && (h + 1 < g))) ? 1 : 0;
        cnt += ((zz.z < zg) || ((zz.z == zg) && (h + 2 < g))) ? 1 : 0;
        cnt += ((zz.w < zg) || ((zz.w == zg) && (h + 3 < g))) ? 1 : 0;
    }
#pragma unroll
    for (int off = 32; off >= 1; off >>= 1)
        cnt += __shfl_down(cnt, off);
    int rank = __shfl(cnt, 0);
    if (lane < 2) {
        ((float4*)(gsorted + rank))[lane] = ((const float4*)(graw + g))[lane];
    }
}

// ---------------------------------------------------------------------------
// Kernel 3: segmented compositing with per-tile circle culling.
// Block = 64 threads = one wave = 16x16 pixel tile, 4 pixels/thread (column).
// Cull: lane i tests gaussian base+i vs tile box (verdict is tile-uniform),
// __ballot -> uniform 64-bit mask, ctz-walk preserves front-to-back order.
// grid (8, 8, NSEG).
// ---------------------------------------------------------------------------
template <int NSEG>
__global__ __launch_bounds__(64) void composite_kernel(
    const PG* __restrict__ gsorted, float4* __restrict__ partial)
{
    constexpr int SEG = NG / NSEG;
    __shared__ float4 sg[SEG * 2];
    const int t = threadIdx.x;
    const int seg = blockIdx.z;
    const int col = blockIdx.x * 16 + (t & 15);
    const int row0 = blockIdx.y * 16 + (t >> 4) * 4;

    const float4* src = (const float4*)(gsorted + seg * SEG);
#pragma unroll
    for (int i = t; i < SEG * 2; i += 64) sg[i] = src[i];
    __syncthreads();

    // tile pixel-center bounds
    const float x0 = blockIdx.x * 16 + 0.5f, x1 = x0 + 15.0f;
    const float y0 = blockIdx.y * 16 + 0.5f, y1 = y0 + 15.0f;

    const float fpx = col + 0.5f;
    const float fpy0 = row0 + 0.5f;
    float T0 = 1.f, T1 = 1.f, T2 = 1.f, T3 = 1.f;
    float Cr0 = 0.f, Cg0 = 0.f, Cb0 = 0.f;
    float Cr1 = 0.f, Cg1 = 0.f, Cb1 = 0.f;
    float Cr2 = 0.f, Cg2 = 0.f, Cb2 = 0.f;
    float Cr3 = 0.f, Cg3 = 0.f, Cb3 = 0.f;

    for (int base = 0; base < SEG; base += 64) {
        // lane t tests gaussian base+t against the tile
        float4 g0 = sg[2 * (base + t) + 0];
        float4 g1 = sg[2 * (base + t) + 1];
        union { float f; __half2 h; } ubr; ubr.f = g1.w;
        float r2 = __half2float(__high2half(ubr.h));
        float dxm = fmaxf(0.f, fmaxf(x0 - g0.x, g0.x - x1));
        float dym = fmaxf(0.f, fmaxf(y0 - g0.y, g0.y - y1));
        bool keep = (dxm * dxm + dym * dym) <= r2;
        unsigned long long mask = __ballot(keep);

        while (mask) {
            int i = base + (int)__builtin_ctzll(mask);
            mask &= (mask - 1);
            float4 f0 = sg[2 * i + 0];
            float4 f1 = sg[2 * i + 1];
            float dx = fpx - f0.x;
            float adx2 = f0.z * dx * dx;
            float bdx = f0.w * dx;
            float alpha = f1.y;
            union { float f; __half2 h; } urg; urg.f = f1.z;
            union { float f; __half2 h; } ubl; ubl.f = f1.w;
            float cr = __half2float(__low2half(urg.h));
            float cg = __half2float(__high2half(urg.h));
            float cb = __half2float(__low2half(ubl.h));

            float dy, p, gv, a, w;

            dy = fpy0 - f0.y;
            p = fminf(fmaf(dy, fmaf(f1.x, dy, bdx), adx2), 0.f);
            gv = exp2f(p);
            a = fminf(0.99f, alpha * gv);
            w = a * T0;
            Cr0 = fmaf(w, cr, Cr0); Cg0 = fmaf(w, cg, Cg0); Cb0 = fmaf(w, cb, Cb0);
            T0 = fmaf(-a, T0, T0);

            dy = (fpy0 + 1.f) - f0.y;
            p = fminf(fmaf(dy, fmaf(f1.x, dy, bdx), adx2), 0.f);
            gv = exp2f(p);
            a = fminf(0.99f, alpha * gv);
            w = a * T1;
            Cr1 = fmaf(w, cr, Cr1); Cg1 = fmaf(w, cg, Cg1); Cb1 = fmaf(w, cb, Cb1);
            T1 = fmaf(-a, T1, T1);

            dy = (fpy0 + 2.f) - f0.y;
            p = fminf(fmaf(dy, fmaf(f1.x, dy, bdx), adx2), 0.f);
            gv = exp2f(p);
            a = fminf(0.99f, alpha * gv);
            w = a * T2;
            Cr2 = fmaf(w, cr, Cr2); Cg2 = fmaf(w, cg, Cg2); Cb2 = fmaf(w, cb, Cb2);
            T2 = fmaf(-a, T2, T2);

            dy = (fpy0 + 3.f) - f0.y;
            p = fminf(fmaf(dy, fmaf(f1.x, dy, bdx), adx2), 0.f);
            gv = exp2f(p);
            a = fminf(0.99f, alpha * gv);
            w = a * T3;
            Cr3 = fmaf(w, cr, Cr3); Cg3 = fmaf(w, cg, Cg3); Cb3 = fmaf(w, cb, Cb3);
            T3 = fmaf(-a, T3, T3);
        }
    }

    float4* dst = partial + (size_t)seg * NPIX + row0 * IMG_W + col;
    dst[0 * IMG_W] = make_float4(Cr0, Cg0, Cb0, T0);
    dst[1 * IMG_W] = make_float4(Cr1, Cg1, Cb1, T1);
    dst[2 * IMG_W] = make_float4(Cr2, Cg2, Cb2, T2);
    dst[3 * IMG_W] = make_float4(Cr3, Cg3, Cb3, T3);
}

// ---------------------------------------------------------------------------
// Kernel 4: in-order combine of NSEG partials + background. 256 blocks x 64.
// ---------------------------------------------------------------------------
template <int NSEG>
__global__ __launch_bounds__(64) void combine_kernel(
    const float4* __restrict__ partial, const float* __restrict__ bg,
    float* __restrict__ out)
{
    int pix = blockIdx.x * 64 + threadIdx.x;
    float T = 1.0f, Cr = 0.0f, Cg = 0.0f, Cb = 0.0f;
#pragma unroll
    for (int s = 0; s < NSEG; ++s) {
        float4 p = partial[s * NPIX + pix];
        Cr = fmaf(T, p.x, Cr);
        Cg = fmaf(T, p.y, Cg);
        Cb = fmaf(T, p.z, Cb);
        T *= p.w;
    }
    out[pix * 3 + 0] = Cr + T * bg[0];
    out[pix * 3 + 1] = Cg + T * bg[1];
    out[pix * 3 + 2] = Cb + T * bg[2];
}

template <int NSEG>
static void launch_pipeline(const float* mean, const float* qvec,
                            const float* svec_raw, const float* color_raw,
                            const float* alpha_raw, const float* bg,
                            const float* viewmat, const float* intrins,
                            float* out, char* ws, hipStream_t stream)
{
    PG* graw      = (PG*)ws;                          // 64 KiB
    float* zbuf   = (float*)(ws + NG * sizeof(PG));   // 8 KiB
    PG* gsorted   = (PG*)(ws + NG * sizeof(PG) + NG * sizeof(float));
    float4* partial = (float4*)(ws + 2 * NG * sizeof(PG) + NG * sizeof(float));

    hipLaunchKernelGGL(prep_kernel, dim3(NG / 256), dim3(256), 0, stream,
                       mean, qvec, svec_raw, color_raw, alpha_raw, viewmat,
                       intrins, graw, zbuf);
    hipLaunchKernelGGL(rank_scatter_kernel, dim3(NG * 64 / 256), dim3(256),
                       0, stream, zbuf, graw, gsorted);
    hipLaunchKernelGGL((composite_kernel<NSEG>), dim3(8, 8, NSEG), dim3(64),
                       0, stream, gsorted, partial);
    hipLaunchKernelGGL((combine_kernel<NSEG>), dim3(NPIX / 64), dim3(64),
                       0, stream, partial, bg, out);
}

extern "C" void kernel_launch(void* const* d_in, const int* in_sizes, int n_in,
                              void* d_out, int out_size, void* d_ws, size_t ws_size,
                              hipStream_t stream)
{
    const float* mean      = (const float*)d_in[0];
    const float* qvec      = (const float*)d_in[1];
    const float* svec_raw  = (const float*)d_in[2];
    const float* color_raw = (const float*)d_in[3];
    const float* alpha_raw = (const float*)d_in[4];
    const float* bg        = (const float*)d_in[5];
    const float* viewmat   = (const float*)d_in[6];
    const float* intrins   = (const float*)d_in[7];
    char* ws = (char*)d_ws;
    float* out = (float*)d_out;

    const size_t fixed = 2 * NG * sizeof(PG) + NG * sizeof(float);
    if (ws_size >= fixed + (size_t)32 * NPIX * sizeof(float4)) {
        launch_pipeline<32>(mean, qvec, svec_raw, color_raw, alpha_raw, bg,
                            viewmat, intrins, out, ws, stream);
    } else if (ws_size >= fixed + (size_t)16 * NPIX * sizeof(float4)) {
        launch_pipeline<16>(mean, qvec, svec_raw, color_raw, alpha_raw, bg,
                            viewmat, intrins, out, ws, stream);
    } else {
        launch_pipeline<8>(mean, qvec, svec_raw, color_raw, alpha_raw, bg,
                           viewmat, intrins, out, ws, stream);
    }
}